// Round 5
// baseline (292.011 us; speedup 1.0000x reference)
//
#include <hip/hip_runtime.h>
#include <cstdint>
#include <cstddef>

#define B_DIM 2048
#define D_DIM 64
#define N_DIM 16384
#define H_DIM 4
#define DOUT_DIM 256
#define NOUT (H_DIM*DOUT_DIM)   // 1024

typedef __bf16 bf16;
typedef __bf16 bf16x4 __attribute__((ext_vector_type(4)));
typedef __bf16 bf16x8 __attribute__((ext_vector_type(8)));
typedef float f32x4 __attribute__((ext_vector_type(4)));

#define LOG2E 1.44269504088896340736f

// ---------------------------------------------------------------------------
// K0: fused prep.
//   blocks [0, 4096)    : split R into bf16 hi/lo + r2[n] = ||r_n||^2 (4 rows/block)
//   blocks [4096, 4608) : split 2*x into bf16 hi/lo (2x folds the score's factor of 2)
#define PREP_RBLK 4096
#define PREP_XBLK 512
__global__ void k_prep(const float* __restrict__ x, const float* __restrict__ R,
                       bf16* __restrict__ xh, bf16* __restrict__ xl,
                       bf16* __restrict__ Rh, bf16* __restrict__ Rl,
                       float* __restrict__ r2) {
    int blk = blockIdx.x, t = threadIdx.x;
    if (blk < PREP_RBLK) {
        int lane = t & 63, wave = t >> 6;
        int row = blk * 4 + wave;
        float v = R[row * 64 + lane];
        bf16 h = (bf16)v;
        Rh[row * 64 + lane] = h;
        Rl[row * 64 + lane] = (bf16)(v - (float)h);
        float s = v * v;
        #pragma unroll
        for (int off = 32; off > 0; off >>= 1) s += __shfl_xor(s, off, 64);
        if (lane == 0) r2[row] = s;
    } else {
        int i = (blk - PREP_RBLK) * 256 + t;        // B*D = 131072 total
        float f = 2.0f * x[i];
        bf16 h = (bf16)f;
        xh[i] = h;
        xl[i] = (bf16)(f - (float)h);
    }
}

// K0d: Vt[h*256+d][n] = bf16(W[h][n][d] / (relu(q[h][n])+eps))
// 64n x 32d tile; write side emits bf16x8 (full 128B line segments).
__global__ void k_build_V(const float* __restrict__ W, const float* __restrict__ q_raw,
                          bf16* __restrict__ Vt) {
    __shared__ float tile[64][33];
    __shared__ float qprow[64];
    int h = blockIdx.z, d0 = blockIdx.y * 32, n0 = blockIdx.x * 64;
    int t = threadIdx.x;
    int tj = t & 31, ti = t >> 5;   // ti: 0..7
    if (t < 64)
        qprow[t] = 1.0f / (fmaxf(q_raw[h * N_DIM + n0 + t], 0.0f) + 1e-12f);
    #pragma unroll
    for (int ii = 0; ii < 8; ++ii) {
        int i = ti + ii * 8;        // n-local 0..63
        tile[i][tj] = W[((size_t)(h * N_DIM) + (n0 + i)) * DOUT_DIM + d0 + tj];
    }
    __syncthreads();
    int d = t >> 3, nq = t & 7;     // d-local 0..31, n-quad 0..7
    bf16x8 ov;
    #pragma unroll
    for (int j = 0; j < 8; ++j) {
        int n = nq * 8 + j;
        ov[j] = (bf16)(tile[n][d] * qprow[n]);
    }
    *(bf16x8*)(Vt + (size_t)(h * DOUT_DIM + d0 + d) * N_DIM + n0 + nq * 8) = ov;
}

// K2: scores via split-bf16 MFMA (3 products), e = exp(s) -> bf16 (no shift:
// softmax is shift-invariant; s in [-30,12] so e fits bf16 and fp32 sums are
// safe).  S partials go to Spart[ktile][b][h] via plain coalesced stores.
// UNCHANGED (single-variable A/B: only k_gemm changes this round).
__launch_bounds__(256)
__global__ void k_scores(const bf16* __restrict__ xh, const bf16* __restrict__ xl,
                         const bf16* __restrict__ Rh, const bf16* __restrict__ Rl,
                         const float* __restrict__ r2, const float* __restrict__ q_raw,
                         bf16* __restrict__ e, float* __restrict__ Spart) {
    __shared__ bf16 eT[128][136];   // [b-local][key-local], padded rows
    __shared__ float qp[4][128];
    int n0 = blockIdx.x * 128;      // key tile
    int row0 = blockIdx.y * 128;    // b tile
    int t = threadIdx.x;
    int lane = t & 63, w = t >> 6;
    int wr = w >> 1, wc = w & 1;    // wave owns keys wr*64.., b's wc*64..
    #pragma unroll
    for (int rr = 0; rr < 2; ++rr) {
        int ii = t + rr * 256;      // 0..511 = 4 heads x 128 keys
        qp[ii >> 7][ii & 127] =
            1.0f / (fmaxf(q_raw[(ii >> 7) * N_DIM + n0 + (ii & 127)], 0.0f) + 1e-12f);
    }
    int l15 = lane & 15, l4 = lane >> 4;
    f32x4 acc[4][4] = {};
    #pragma unroll
    for (int kk = 0; kk < 2; ++kk) {
        bf16x8 bxh[4], bxl[4];
        #pragma unroll
        for (int ni = 0; ni < 4; ++ni) {
            int b = row0 + wc * 64 + ni * 16 + l15;
            size_t off = (size_t)b * 64 + kk * 32 + l4 * 8;
            bxh[ni] = *(const bf16x8*)(xh + off);
            bxl[ni] = *(const bf16x8*)(xl + off);
        }
        #pragma unroll
        for (int mi = 0; mi < 4; ++mi) {
            int n = n0 + wr * 64 + mi * 16 + l15;
            size_t off = (size_t)n * 64 + kk * 32 + l4 * 8;
            bf16x8 arh = *(const bf16x8*)(Rh + off);
            bf16x8 arl = *(const bf16x8*)(Rl + off);
            #pragma unroll
            for (int ni = 0; ni < 4; ++ni) {
                acc[mi][ni] = __builtin_amdgcn_mfma_f32_16x16x32_bf16(arh, bxh[ni], acc[mi][ni], 0, 0, 0);
                acc[mi][ni] = __builtin_amdgcn_mfma_f32_16x16x32_bf16(arh, bxl[ni], acc[mi][ni], 0, 0, 0);
                acc[mi][ni] = __builtin_amdgcn_mfma_f32_16x16x32_bf16(arl, bxh[ni], acc[mi][ni], 0, 0, 0);
            }
        }
    }
    // epilogue: s = acc - r2; e = exp(s) -> bf16 into LDS (transposed)
    #pragma unroll
    for (int mi = 0; mi < 4; ++mi) {
        int keyb = wr * 64 + mi * 16 + l4 * 4;          // 4 consecutive local keys
        f32x4 r2v = *(const f32x4*)(r2 + n0 + keyb);
        #pragma unroll
        for (int ni = 0; ni < 4; ++ni) {
            int bloc = wc * 64 + ni * 16 + l15;
            bf16x4 ev;
            #pragma unroll
            for (int j = 0; j < 4; ++j) {
                float s = acc[mi][ni][j] - r2v[j];
                ev[j] = (bf16)exp2f(s * LOG2E);
            }
            *(bf16x4*)(&eT[bloc][keyb]) = ev;
        }
    }
    __syncthreads();
    // cooperative coalesced e store + S partial accumulation (same bf16 e as
    // the numerator GEMM -> first-order error cancellation in the ratio)
    {
        int bloc = t >> 1, half = t & 1;
        int b = row0 + bloc;
        bf16x8 chunk[8];
        #pragma unroll
        for (int i = 0; i < 8; ++i)
            chunk[i] = *(const bf16x8*)(&eT[bloc][half * 64 + i * 8]);
        bf16x8* gp = (bf16x8*)(e + (size_t)b * N_DIM + n0 + half * 64);
        #pragma unroll
        for (int i = 0; i < 8; ++i) gp[i] = chunk[i];
        float s0 = 0, s1 = 0, s2 = 0, s3 = 0;
        #pragma unroll
        for (int i = 0; i < 8; ++i) {
            #pragma unroll
            for (int jj = 0; jj < 8; ++jj) {
                int nl = half * 64 + i * 8 + jj;
                float ef = (float)chunk[i][jj];
                s0 += ef * qp[0][nl]; s1 += ef * qp[1][nl];
                s2 += ef * qp[2][nl]; s3 += ef * qp[3][nl];
            }
        }
        // pair-combine halves (lanes t, t^1 are in the same wave)
        s0 += __shfl_xor(s0, 1, 64);
        s1 += __shfl_xor(s1, 1, 64);
        s2 += __shfl_xor(s2, 1, 64);
        s3 += __shfl_xor(s3, 1, 64);
        if (half == 0) {
            f32x4 sv = {s0, s1, s2, s3};
            *(f32x4*)(Spart + ((size_t)blockIdx.x * B_DIM + b) * 4) = sv;
        }
    }
}

// K2b: Sinv[b][h] = 1 / (sum_kt Spart[kt][b][h] + eps)
__global__ void k_sreduce(const float* __restrict__ Spart, float* __restrict__ Sinv) {
    int i = blockIdx.x * 256 + threadIdx.x;     // 8192 = 2048*4
    float s = 0.f;
    #pragma unroll 8
    for (int kt = 0; kt < N_DIM / 128; ++kt) s += Spart[(size_t)kt * (B_DIM * 4) + i];
    Sinv[i] = 1.0f / (s + 1e-12f);
}

// K3: split-K GEMM  parts[z][2048][1024] = e @ Vt^T (K-slice z)
// m97 structure: 128x128 tile, BK=64, global_load_lds width 16. Plain stores.
// ROUND 4/5: XCD-aware chunked swizzle (T1). Round-3 counters: FETCH_SIZE=279MB
// vs 96MB ideal -- consecutive-x blocks (which share a 512KB A-panel slice)
// were round-robined across 8 XCDs, so every XCD L2 re-fetched every panel.
// Remap orig=(flat%8)*cpx+flat/8 (bijective; nwg%8==0 for ksplit 2/4/8):
// each XCD gets one contiguous chunk (ksplit=8: exactly one K-slice), x
// varies fastest inside -> A-panel sharers stay on one XCD; B set ~4MB ~ L2.
__launch_bounds__(256)
__global__ void k_gemm(const bf16* __restrict__ e, const bf16* __restrict__ Vt,
                       float* __restrict__ parts, int kiters) {
    __shared__ bf16 As[128 * 64];
    __shared__ bf16 Bs[128 * 64];
    int t = threadIdx.x;
    int lane = t & 63, w = t >> 6;
    int wr = w >> 1, wc = w & 1;
    // --- XCD swizzle ---
    int nwg = gridDim.x * gridDim.y * gridDim.z;
    int cpx = nwg >> 3;                  // chunk per XCD
    int flat = blockIdx.x + 8 * (blockIdx.y + 16 * blockIdx.z);
    int orig = (flat & 7) * cpx + (flat >> 3);
    int bx = orig & 7;                   // bcol tile (x fastest: A-panel sharers together)
    int by = (orig >> 3) & 15;           // brow tile
    int bz = orig >> 7;                  // K-slice
    int brow = by * 128;
    int bcol = bx * 128;
    int kbase = bz * kiters * 64;
    int l15 = lane & 15, l4 = lane >> 4;
    int srcRow = lane >> 3;              // 0..7 within a wave's 8-row chunk
    int srcColB = (lane & 7) * 16;       // byte offset within a 128B row
    f32x4 acc[4][4] = {};
    for (int kt = 0; kt < kiters; ++kt) {
        int k0 = kbase + kt * 64;
        #pragma unroll
        for (int j = 0; j < 4; ++j) {
            int chunk = j * 4 + w;       // 0..15, wave-uniform
            int row = chunk * 8 + srcRow;
            const char* gA = (const char*)e + ((size_t)(brow + row) * N_DIM + k0) * 2 + srcColB;
            __builtin_amdgcn_global_load_lds((const __attribute__((address_space(1))) void*)gA,
                (__attribute__((address_space(3))) void*)((char*)As + chunk * 1024), 16, 0, 0);
            const char* gB = (const char*)Vt + ((size_t)(bcol + row) * N_DIM + k0) * 2 + srcColB;
            __builtin_amdgcn_global_load_lds((const __attribute__((address_space(1))) void*)gB,
                (__attribute__((address_space(3))) void*)((char*)Bs + chunk * 1024), 16, 0, 0);
        }
        __syncthreads();
        #pragma unroll
        for (int kk = 0; kk < 2; ++kk) {
            bf16x8 bfr[4];
            #pragma unroll
            for (int ni = 0; ni < 4; ++ni)
                bfr[ni] = *(const bf16x8*)(Bs + (wc * 64 + ni * 16 + l15) * 64 + kk * 32 + l4 * 8);
            #pragma unroll
            for (int mi = 0; mi < 4; ++mi) {
                bf16x8 afr = *(const bf16x8*)(As + (wr * 64 + mi * 16 + l15) * 64 + kk * 32 + l4 * 8);
                #pragma unroll
                for (int ni = 0; ni < 4; ++ni)
                    acc[mi][ni] = __builtin_amdgcn_mfma_f32_16x16x32_bf16(afr, bfr[ni], acc[mi][ni], 0, 0, 0);
            }
        }
        __syncthreads();
    }
    float* P = parts + (size_t)bz * ((size_t)B_DIM * NOUT);
    #pragma unroll
    for (int mi = 0; mi < 4; ++mi) {
        #pragma unroll
        for (int j = 0; j < 4; ++j) {
            int r = brow + wr * 64 + mi * 16 + l4 * 4 + j;
            #pragma unroll
            for (int ni = 0; ni < 4; ++ni) {
                int c = bcol + wc * 64 + ni * 16 + l15;
                P[(size_t)r * NOUT + c] = acc[mi][ni][j];
            }
        }
    }
}

// K4: out[b][c] = (sum_z parts[z][b][c]) * Sinv[b][c>>8]   (f32x4 per thread)
__global__ void k_final(const float* __restrict__ parts, const float* __restrict__ Sinv,
                        float* __restrict__ out, int nks) {
    int i4 = blockIdx.x * 256 + threadIdx.x;    // 524288 quads
    size_t base = (size_t)i4 * 4;
    f32x4 s = {0.f, 0.f, 0.f, 0.f};
    for (int k = 0; k < nks; ++k)
        s += *(const f32x4*)(parts + (size_t)k * ((size_t)B_DIM * NOUT) + base);
    int b = i4 >> 8;                 // (i4*4) >> 10
    int c = (i4 << 2) & 1023;        // head boundary (256) can't split a quad
    float inv = Sinv[b * 4 + (c >> 8)];
    *(f32x4*)(out + base) = s * inv;
}

extern "C" void kernel_launch(void* const* d_in, const int* in_sizes, int n_in,
                              void* d_out, int out_size, void* d_ws, size_t ws_size,
                              hipStream_t stream) {
    const float* x     = (const float*)d_in[0];   // (2048, 64)
    const float* R     = (const float*)d_in[1];   // (16384, 64)
    const float* q_raw = (const float*)d_in[2];   // (4, 16384)
    const float* W     = (const float*)d_in[3];   // (4, 16384, 256)
    float* out = (float*)d_out;                    // (2048, 4, 256)

    char* ws = (char*)d_ws;
    size_t off = 0;
    auto alloc = [&](size_t bytes) {
        void* p = ws + off;
        off += (bytes + 255) & ~(size_t)255;
        return p;
    };
    bf16*  Vt    = (bf16*) alloc((size_t)NOUT * N_DIM * 2);          // 32 MB
    bf16*  eM    = (bf16*) alloc((size_t)B_DIM * N_DIM * 2);         // 64 MB
    bf16*  xh    = (bf16*) alloc((size_t)B_DIM * D_DIM * 2);
    bf16*  xl    = (bf16*) alloc((size_t)B_DIM * D_DIM * 2);
    bf16*  Rh    = (bf16*) alloc((size_t)N_DIM * D_DIM * 2);
    bf16*  Rl    = (bf16*) alloc((size_t)N_DIM * D_DIM * 2);
    float* r2    = (float*)alloc((size_t)N_DIM * 4);
    float* Spart = (float*)alloc((size_t)(N_DIM / 128) * B_DIM * 4 * 4);  // 4 MB
    float* Sinv  = (float*)alloc((size_t)B_DIM * H_DIM * 4);
    (void)n_in; (void)in_sizes;

    const size_t PART_BYTES = (size_t)B_DIM * NOUT * 4;              // 8 MB
    int ksplit = (ws_size >= off + 8 * PART_BYTES) ? 8
               : (ws_size >= off + 4 * PART_BYTES) ? 4 : 2;
    float* parts = (float*)alloc((size_t)ksplit * PART_BYTES);
    int kiters = N_DIM / (64 * ksplit);

    k_prep<<<dim3(PREP_RBLK + PREP_XBLK), 256, 0, stream>>>(x, R, xh, xl, Rh, Rl, r2);
    k_build_V<<<dim3(N_DIM / 64, DOUT_DIM / 32, H_DIM), 256, 0, stream>>>(W, q_raw, Vt);
    k_scores<<<dim3(N_DIM / 128, B_DIM / 128), 256, 0, stream>>>(xh, xl, Rh, Rl, r2, q_raw, eM, Spart);
    k_sreduce<<<dim3(B_DIM * H_DIM / 256), 256, 0, stream>>>(Spart, Sinv);
    k_gemm<<<dim3(NOUT / 128, B_DIM / 128, ksplit), 256, 0, stream>>>(eM, Vt, parts, kiters);
    k_final<<<dim3(B_DIM * NOUT / 4 / 256), 256, 0, stream>>>(parts, Sinv, out, ksplit);
}

// Round 9
// 284.406 us; speedup vs baseline: 1.0267x; 1.0267x over previous
//
#include <hip/hip_runtime.h>
#include <cstdint>
#include <cstddef>

#define B_DIM 2048
#define D_DIM 64
#define N_DIM 16384
#define H_DIM 4
#define DOUT_DIM 256
#define NOUT (H_DIM*DOUT_DIM)   // 1024

typedef __bf16 bf16;
typedef __bf16 bf16x4 __attribute__((ext_vector_type(4)));
typedef __bf16 bf16x8 __attribute__((ext_vector_type(8)));
typedef float f32x4 __attribute__((ext_vector_type(4)));

#define LOG2E 1.44269504088896340736f

// ---------------------------------------------------------------------------
// K0: fused prep.
#define PREP_RBLK 4096
#define PREP_XBLK 512
__global__ void k_prep(const float* __restrict__ x, const float* __restrict__ R,
                       bf16* __restrict__ xh, bf16* __restrict__ xl,
                       bf16* __restrict__ Rh, bf16* __restrict__ Rl,
                       float* __restrict__ r2) {
    int blk = blockIdx.x, t = threadIdx.x;
    if (blk < PREP_RBLK) {
        int lane = t & 63, wave = t >> 6;
        int row = blk * 4 + wave;
        float v = R[row * 64 + lane];
        bf16 h = (bf16)v;
        Rh[row * 64 + lane] = h;
        Rl[row * 64 + lane] = (bf16)(v - (float)h);
        float s = v * v;
        #pragma unroll
        for (int off = 32; off > 0; off >>= 1) s += __shfl_xor(s, off, 64);
        if (lane == 0) r2[row] = s;
    } else {
        int i = (blk - PREP_RBLK) * 256 + t;        // B*D = 131072 total
        float f = 2.0f * x[i];
        bf16 h = (bf16)f;
        xh[i] = h;
        xl[i] = (bf16)(f - (float)h);
    }
}

// K0d: Vt[h*256+d][n] = bf16(W[h][n][d] / (relu(q[h][n])+eps))
__global__ void k_build_V(const float* __restrict__ W, const float* __restrict__ q_raw,
                          bf16* __restrict__ Vt) {
    __shared__ float tile[64][33];
    __shared__ float qprow[64];
    int h = blockIdx.z, d0 = blockIdx.y * 32, n0 = blockIdx.x * 64;
    int t = threadIdx.x;
    int tj = t & 31, ti = t >> 5;   // ti: 0..7
    if (t < 64)
        qprow[t] = 1.0f / (fmaxf(q_raw[h * N_DIM + n0 + t], 0.0f) + 1e-12f);
    #pragma unroll
    for (int ii = 0; ii < 8; ++ii) {
        int i = ti + ii * 8;        // n-local 0..63
        tile[i][tj] = W[((size_t)(h * N_DIM) + (n0 + i)) * DOUT_DIM + d0 + tj];
    }
    __syncthreads();
    int d = t >> 3, nq = t & 7;     // d-local 0..31, n-quad 0..7
    bf16x8 ov;
    #pragma unroll
    for (int j = 0; j < 8; ++j) {
        int n = nq * 8 + j;
        ov[j] = (bf16)(tile[n][d] * qprow[n]);
    }
    *(bf16x8*)(Vt + (size_t)(h * DOUT_DIM + d0 + d) * N_DIM + n0 + nq * 8) = ov;
}

// K2: scores via split-bf16 MFMA (3 products), e = exp(s) -> bf16.
// UNCHANGED (single-variable round: only k_gemm changes).
__launch_bounds__(256)
__global__ void k_scores(const bf16* __restrict__ xh, const bf16* __restrict__ xl,
                         const bf16* __restrict__ Rh, const bf16* __restrict__ Rl,
                         const float* __restrict__ r2, const float* __restrict__ q_raw,
                         bf16* __restrict__ e, float* __restrict__ Spart) {
    __shared__ bf16 eT[128][136];   // [b-local][key-local], padded rows
    __shared__ float qp[4][128];
    int n0 = blockIdx.x * 128;      // key tile
    int row0 = blockIdx.y * 128;    // b tile
    int t = threadIdx.x;
    int lane = t & 63, w = t >> 6;
    int wr = w >> 1, wc = w & 1;    // wave owns keys wr*64.., b's wc*64..
    #pragma unroll
    for (int rr = 0; rr < 2; ++rr) {
        int ii = t + rr * 256;      // 0..511 = 4 heads x 128 keys
        qp[ii >> 7][ii & 127] =
            1.0f / (fmaxf(q_raw[(ii >> 7) * N_DIM + n0 + (ii & 127)], 0.0f) + 1e-12f);
    }
    int l15 = lane & 15, l4 = lane >> 4;
    f32x4 acc[4][4] = {};
    #pragma unroll
    for (int kk = 0; kk < 2; ++kk) {
        bf16x8 bxh[4], bxl[4];
        #pragma unroll
        for (int ni = 0; ni < 4; ++ni) {
            int b = row0 + wc * 64 + ni * 16 + l15;
            size_t off = (size_t)b * 64 + kk * 32 + l4 * 8;
            bxh[ni] = *(const bf16x8*)(xh + off);
            bxl[ni] = *(const bf16x8*)(xl + off);
        }
        #pragma unroll
        for (int mi = 0; mi < 4; ++mi) {
            int n = n0 + wr * 64 + mi * 16 + l15;
            size_t off = (size_t)n * 64 + kk * 32 + l4 * 8;
            bf16x8 arh = *(const bf16x8*)(Rh + off);
            bf16x8 arl = *(const bf16x8*)(Rl + off);
            #pragma unroll
            for (int ni = 0; ni < 4; ++ni) {
                acc[mi][ni] = __builtin_amdgcn_mfma_f32_16x16x32_bf16(arh, bxh[ni], acc[mi][ni], 0, 0, 0);
                acc[mi][ni] = __builtin_amdgcn_mfma_f32_16x16x32_bf16(arh, bxl[ni], acc[mi][ni], 0, 0, 0);
                acc[mi][ni] = __builtin_amdgcn_mfma_f32_16x16x32_bf16(arl, bxh[ni], acc[mi][ni], 0, 0, 0);
            }
        }
    }
    #pragma unroll
    for (int mi = 0; mi < 4; ++mi) {
        int keyb = wr * 64 + mi * 16 + l4 * 4;          // 4 consecutive local keys
        f32x4 r2v = *(const f32x4*)(r2 + n0 + keyb);
        #pragma unroll
        for (int ni = 0; ni < 4; ++ni) {
            int bloc = wc * 64 + ni * 16 + l15;
            bf16x4 ev;
            #pragma unroll
            for (int j = 0; j < 4; ++j) {
                float s = acc[mi][ni][j] - r2v[j];
                ev[j] = (bf16)exp2f(s * LOG2E);
            }
            *(bf16x4*)(&eT[bloc][keyb]) = ev;
        }
    }
    __syncthreads();
    {
        int bloc = t >> 1, half = t & 1;
        int b = row0 + bloc;
        bf16x8 chunk[8];
        #pragma unroll
        for (int i = 0; i < 8; ++i)
            chunk[i] = *(const bf16x8*)(&eT[bloc][half * 64 + i * 8]);
        bf16x8* gp = (bf16x8*)(e + (size_t)b * N_DIM + n0 + half * 64);
        #pragma unroll
        for (int i = 0; i < 8; ++i) gp[i] = chunk[i];
        float s0 = 0, s1 = 0, s2 = 0, s3 = 0;
        #pragma unroll
        for (int i = 0; i < 8; ++i) {
            #pragma unroll
            for (int jj = 0; jj < 8; ++jj) {
                int nl = half * 64 + i * 8 + jj;
                float ef = (float)chunk[i][jj];
                s0 += ef * qp[0][nl]; s1 += ef * qp[1][nl];
                s2 += ef * qp[2][nl]; s3 += ef * qp[3][nl];
            }
        }
        s0 += __shfl_xor(s0, 1, 64);
        s1 += __shfl_xor(s1, 1, 64);
        s2 += __shfl_xor(s2, 1, 64);
        s3 += __shfl_xor(s3, 1, 64);
        if (half == 0) {
            f32x4 sv = {s0, s1, s2, s3};
            *(f32x4*)(Spart + ((size_t)blockIdx.x * B_DIM + b) * 4) = sv;
        }
    }
}

// K2b: Sinv[b][h] = 1 / (sum_kt Spart[kt][b][h] + eps)
__global__ void k_sreduce(const float* __restrict__ Spart, float* __restrict__ Sinv) {
    int i = blockIdx.x * 256 + threadIdx.x;     // 8192 = 2048*4
    float s = 0.f;
    #pragma unroll 8
    for (int kt = 0; kt < N_DIM / 128; ++kt) s += Spart[(size_t)kt * (B_DIM * 4) + i];
    Sinv[i] = 1.0f / (s + 1e-12f);
}

// K3: split-K GEMM  parts[z][2048][1024] = e @ Vt^T (K-slice z)
// Deep-pipeline restructure (round-5 A/B: FETCH 279->70MB but dur null at
// 114us; MfmaUtil 25%, LDS_BANK_CONFLICT 25.2M -> the 2-barrier
// vmcnt(0)-drain lockstep + 16-way LDS read conflict are the serializers).
//   - 4-deep LDS buffers (128KB), prefetch distance 3
//   - counted s_waitcnt vmcnt(24) (16/8/0 tail) - never drains in steady
//     state; raw asm s_barrier (no __syncthreads -> no compiler vmcnt(0))
//   - T2 XOR swizzle both sides (rule #21): pre-swizzled gload SOURCE col +
//     swizzled ds_read; LDS dest linear. Read banks: full 32-bank spread,
//     2-way aliasing only (free, m136).
//   - s_setprio(1) around the 32-MFMA cluster (T5).
// vmcnt ledger: 8 gload-lds/wave/STAGE; 3 in flight -> vmcnt(24) retires
// exactly tile t; per-wave wait + s_barrier => block-wide visibility.
// WAR: compute(t-1)'s ds_reads complete before its trailing barrier;
// STAGE(t+3) (same buffer) issues after it. Known risk: 128KB LDS -> 1
// block/CU; depth-3 prefetch (~600-750cy lead) must cover memory latency.
__launch_bounds__(256)
__global__ void k_gemm(const bf16* __restrict__ e, const bf16* __restrict__ Vt,
                       float* __restrict__ parts, int kiters) {
    __shared__ bf16 AB[4][2][8192];      // [buf][A/B][128 rows x 64 k] = 128 KB
    int t = threadIdx.x;
    int lane = t & 63, w = t >> 6;
    int wr = w >> 1, wc = w & 1;
    // --- XCD swizzle (kept from round 4: FETCH 279->70MB) ---
    int nwg = gridDim.x * gridDim.y * gridDim.z;
    int cpx = nwg >> 3;
    int flat = blockIdx.x + 8 * (blockIdx.y + 16 * blockIdx.z);
    int orig = (flat & 7) * cpx + (flat >> 3);
    int bx = orig & 7;
    int by = (orig >> 3) & 15;
    int bz = orig >> 7;
    int brow = by * 128;
    int bcol = bx * 128;
    int kbase = bz * kiters * 64;
    int l15 = lane & 15, l4 = lane >> 4;
    const char* eC  = (const char*)e;
    const char* VtC = (const char*)Vt;
    // pre-swizzled source column within the 128B row segment:
    // dest (linear) col = (lane&7)*16, row&7 = lane>>3  ->  src col = dest ^ ((row&7)<<4)
    int scolswz = (((lane & 7) ^ (lane >> 3)) << 4);
    int srow = lane >> 3;

#define STAGE(bi, tile) do {                                                              \
    size_t acol = (size_t)(kbase + (tile) * 64) * 2 + scolswz;                            \
    _Pragma("unroll")                                                                     \
    for (int j_ = 0; j_ < 4; ++j_) {                                                      \
        int chunk_ = j_ * 4 + w;                                                          \
        int row_ = chunk_ * 8 + srow;                                                     \
        __builtin_amdgcn_global_load_lds(                                                 \
            (const __attribute__((address_space(1))) void*)(eC + (size_t)(brow + row_) * (N_DIM*2) + acol), \
            (__attribute__((address_space(3))) void*)((char*)&AB[bi][0][0] + chunk_ * 1024), 16, 0, 0); \
        __builtin_amdgcn_global_load_lds(                                                 \
            (const __attribute__((address_space(1))) void*)(VtC + (size_t)(bcol + row_) * (N_DIM*2) + acol), \
            (__attribute__((address_space(3))) void*)((char*)&AB[bi][1][0] + chunk_ * 1024), 16, 0, 0); \
    }                                                                                     \
} while (0)

#define COMPUTE(bi) do {                                                                  \
    const bf16* As_ = &AB[bi][0][0];                                                      \
    const bf16* Bs_ = &AB[bi][1][0];                                                      \
    _Pragma("unroll")                                                                     \
    for (int kk = 0; kk < 2; ++kk) {                                                      \
        bf16x8 bfr[4], afr[4];                                                            \
        _Pragma("unroll")                                                                 \
        for (int ni = 0; ni < 4; ++ni) {                                                  \
            int row_ = wc * 64 + ni * 16 + l15;                                           \
            int col_ = (kk * 32 + l4 * 8) ^ ((row_ & 7) << 3);                            \
            bfr[ni] = *(const bf16x8*)(Bs_ + row_ * 64 + col_);                           \
        }                                                                                 \
        _Pragma("unroll")                                                                 \
        for (int mi = 0; mi < 4; ++mi) {                                                  \
            int row_ = wr * 64 + mi * 16 + l15;                                           \
            int col_ = (kk * 32 + l4 * 8) ^ ((row_ & 7) << 3);                            \
            afr[mi] = *(const bf16x8*)(As_ + row_ * 64 + col_);                           \
        }                                                                                 \
        _Pragma("unroll")                                                                 \
        for (int mi = 0; mi < 4; ++mi)                                                    \
            _Pragma("unroll")                                                             \
            for (int ni = 0; ni < 4; ++ni)                                                \
                acc[mi][ni] = __builtin_amdgcn_mfma_f32_16x16x32_bf16(afr[mi], bfr[ni], acc[mi][ni], 0, 0, 0); \
    }                                                                                     \
} while (0)

    f32x4 acc[4][4] = {};
    // prologue: prefetch tiles 0,1,2 into bufs 0,1,2 (24 loads in flight)
    STAGE(0, 0);
    STAGE(1, 1);
    STAGE(2, 2);
    // main loop: stage t+3, wait for t (24 newer stay in flight), compute t
    for (int kt = 0; kt <= kiters - 4; ++kt) {
        int bi = kt & 3;
        STAGE((kt + 3) & 3, kt + 3);
        asm volatile("s_waitcnt vmcnt(24)" ::: "memory");
        __builtin_amdgcn_sched_barrier(0);
        asm volatile("s_barrier" ::: "memory");
        __builtin_amdgcn_s_setprio(1);
        COMPUTE(bi);
        __builtin_amdgcn_s_setprio(0);
        asm volatile("s_barrier" ::: "memory");
    }
    // 3-step tail: vmcnt 16 / 8 / 0
    {
        asm volatile("s_waitcnt vmcnt(16)" ::: "memory");
        __builtin_amdgcn_sched_barrier(0);
        asm volatile("s_barrier" ::: "memory");
        COMPUTE((kiters - 3) & 3);
        asm volatile("s_barrier" ::: "memory");
    }
    {
        asm volatile("s_waitcnt vmcnt(8)" ::: "memory");
        __builtin_amdgcn_sched_barrier(0);
        asm volatile("s_barrier" ::: "memory");
        COMPUTE((kiters - 2) & 3);
        asm volatile("s_barrier" ::: "memory");
    }
    {
        asm volatile("s_waitcnt vmcnt(0)" ::: "memory");
        __builtin_amdgcn_sched_barrier(0);
        asm volatile("s_barrier" ::: "memory");
        COMPUTE((kiters - 1) & 3);
    }
#undef STAGE
#undef COMPUTE
    float* P = parts + (size_t)bz * ((size_t)B_DIM * NOUT);
    #pragma unroll
    for (int mi = 0; mi < 4; ++mi) {
        #pragma unroll
        for (int j = 0; j < 4; ++j) {
            int r = brow + wr * 64 + mi * 16 + l4 * 4 + j;
            #pragma unroll
            for (int ni = 0; ni < 4; ++ni) {
                int c = bcol + wc * 64 + ni * 16 + l15;
                P[(size_t)r * NOUT + c] = acc[mi][ni][j];
            }
        }
    }
}

// K4: out[b][c] = (sum_z parts[z][b][c]) * Sinv[b][c>>8]
__global__ void k_final(const float* __restrict__ parts, const float* __restrict__ Sinv,
                        float* __restrict__ out, int nks) {
    int i4 = blockIdx.x * 256 + threadIdx.x;    // 524288 quads
    size_t base = (size_t)i4 * 4;
    f32x4 s = {0.f, 0.f, 0.f, 0.f};
    for (int k = 0; k < nks; ++k)
        s += *(const f32x4*)(parts + (size_t)k * ((size_t)B_DIM * NOUT) + base);
    int b = i4 >> 8;
    int c = (i4 << 2) & 1023;
    float inv = Sinv[b * 4 + (c >> 8)];
    *(f32x4*)(out + base) = s * inv;
}

extern "C" void kernel_launch(void* const* d_in, const int* in_sizes, int n_in,
                              void* d_out, int out_size, void* d_ws, size_t ws_size,
                              hipStream_t stream) {
    const float* x     = (const float*)d_in[0];   // (2048, 64)
    const float* R     = (const float*)d_in[1];   // (16384, 64)
    const float* q_raw = (const float*)d_in[2];   // (4, 16384)
    const float* W     = (const float*)d_in[3];   // (4, 16384, 256)
    float* out = (float*)d_out;                    // (2048, 4, 256)

    char* ws = (char*)d_ws;
    size_t off = 0;
    auto alloc = [&](size_t bytes) {
        void* p = ws + off;
        off += (bytes + 255) & ~(size_t)255;
        return p;
    };
    bf16*  Vt    = (bf16*) alloc((size_t)NOUT * N_DIM * 2);          // 32 MB
    bf16*  eM    = (bf16*) alloc((size_t)B_DIM * N_DIM * 2);         // 64 MB
    bf16*  xh    = (bf16*) alloc((size_t)B_DIM * D_DIM * 2);
    bf16*  xl    = (bf16*) alloc((size_t)B_DIM * D_DIM * 2);
    bf16*  Rh    = (bf16*) alloc((size_t)N_DIM * D_DIM * 2);
    bf16*  Rl    = (bf16*) alloc((size_t)N_DIM * D_DIM * 2);
    float* r2    = (float*)alloc((size_t)N_DIM * 4);
    float* Spart = (float*)alloc((size_t)(N_DIM / 128) * B_DIM * 4 * 4);  // 4 MB
    float* Sinv  = (float*)alloc((size_t)B_DIM * H_DIM * 4);
    (void)n_in; (void)in_sizes;

    const size_t PART_BYTES = (size_t)B_DIM * NOUT * 4;              // 8 MB
    int ksplit = (ws_size >= off + 8 * PART_BYTES) ? 8
               : (ws_size >= off + 4 * PART_BYTES) ? 4 : 2;
    float* parts = (float*)alloc((size_t)ksplit * PART_BYTES);
    int kiters = N_DIM / (64 * ksplit);

    k_prep<<<dim3(PREP_RBLK + PREP_XBLK), 256, 0, stream>>>(x, R, xh, xl, Rh, Rl, r2);
    k_build_V<<<dim3(N_DIM / 64, DOUT_DIM / 32, H_DIM), 256, 0, stream>>>(W, q_raw, Vt);
    k_scores<<<dim3(N_DIM / 128, B_DIM / 128), 256, 0, stream>>>(xh, xl, Rh, Rl, r2, q_raw, eM, Spart);
    k_sreduce<<<dim3(B_DIM * H_DIM / 256), 256, 0, stream>>>(Spart, Sinv);
    k_gemm<<<dim3(NOUT / 128, B_DIM / 128, ksplit), 256, 0, stream>>>(eM, Vt, parts, kiters);
    k_final<<<dim3(B_DIM * NOUT / 4 / 256), 256, 0, stream>>>(parts, Sinv, out, ksplit);
}

// Round 10
// 255.265 us; speedup vs baseline: 1.1440x; 1.1142x over previous
//
#include <hip/hip_runtime.h>
#include <cstdint>
#include <cstddef>

#define B_DIM 2048
#define D_DIM 64
#define N_DIM 16384
#define H_DIM 4
#define DOUT_DIM 256
#define NOUT (H_DIM*DOUT_DIM)   // 1024

typedef __bf16 bf16;
typedef __bf16 bf16x4 __attribute__((ext_vector_type(4)));
typedef __bf16 bf16x8 __attribute__((ext_vector_type(8)));
typedef float f32x4 __attribute__((ext_vector_type(4)));

#define LOG2E 1.44269504088896340736f

// ---------------------------------------------------------------------------
// K0: fused prep.
#define PREP_RBLK 4096
#define PREP_XBLK 512
__global__ void k_prep(const float* __restrict__ x, const float* __restrict__ R,
                       bf16* __restrict__ xh, bf16* __restrict__ xl,
                       bf16* __restrict__ Rh, bf16* __restrict__ Rl,
                       float* __restrict__ r2) {
    int blk = blockIdx.x, t = threadIdx.x;
    if (blk < PREP_RBLK) {
        int lane = t & 63, wave = t >> 6;
        int row = blk * 4 + wave;
        float v = R[row * 64 + lane];
        bf16 h = (bf16)v;
        Rh[row * 64 + lane] = h;
        Rl[row * 64 + lane] = (bf16)(v - (float)h);
        float s = v * v;
        #pragma unroll
        for (int off = 32; off > 0; off >>= 1) s += __shfl_xor(s, off, 64);
        if (lane == 0) r2[row] = s;
    } else {
        int i = (blk - PREP_RBLK) * 256 + t;        // B*D = 131072 total
        float f = 2.0f * x[i];
        bf16 h = (bf16)f;
        xh[i] = h;
        xl[i] = (bf16)(f - (float)h);
    }
}

// K0d: Vt[h*256+d][n] = bf16(W[h][n][d] / (relu(q[h][n])+eps))
__global__ void k_build_V(const float* __restrict__ W, const float* __restrict__ q_raw,
                          bf16* __restrict__ Vt) {
    __shared__ float tile[64][33];
    __shared__ float qprow[64];
    int h = blockIdx.z, d0 = blockIdx.y * 32, n0 = blockIdx.x * 64;
    int t = threadIdx.x;
    int tj = t & 31, ti = t >> 5;   // ti: 0..7
    if (t < 64)
        qprow[t] = 1.0f / (fmaxf(q_raw[h * N_DIM + n0 + t], 0.0f) + 1e-12f);
    #pragma unroll
    for (int ii = 0; ii < 8; ++ii) {
        int i = ti + ii * 8;        // n-local 0..63
        tile[i][tj] = W[((size_t)(h * N_DIM) + (n0 + i)) * DOUT_DIM + d0 + tj];
    }
    __syncthreads();
    int d = t >> 3, nq = t & 7;     // d-local 0..31, n-quad 0..7
    bf16x8 ov;
    #pragma unroll
    for (int j = 0; j < 8; ++j) {
        int n = nq * 8 + j;
        ov[j] = (bf16)(tile[n][d] * qprow[n]);
    }
    *(bf16x8*)(Vt + (size_t)(h * DOUT_DIM + d0 + d) * N_DIM + n0 + nq * 8) = ov;
}

// K2: scores via split-bf16 MFMA (3 products), e = exp(s) -> bf16.
// UNCHANGED (no counters for it yet; only k_gemm/k_final params change).
__launch_bounds__(256)
__global__ void k_scores(const bf16* __restrict__ xh, const bf16* __restrict__ xl,
                         const bf16* __restrict__ Rh, const bf16* __restrict__ Rl,
                         const float* __restrict__ r2, const float* __restrict__ q_raw,
                         bf16* __restrict__ e, float* __restrict__ Spart) {
    __shared__ bf16 eT[128][136];   // [b-local][key-local], padded rows
    __shared__ float qp[4][128];
    int n0 = blockIdx.x * 128;      // key tile
    int row0 = blockIdx.y * 128;    // b tile
    int t = threadIdx.x;
    int lane = t & 63, w = t >> 6;
    int wr = w >> 1, wc = w & 1;    // wave owns keys wr*64.., b's wc*64..
    #pragma unroll
    for (int rr = 0; rr < 2; ++rr) {
        int ii = t + rr * 256;      // 0..511 = 4 heads x 128 keys
        qp[ii >> 7][ii & 127] =
            1.0f / (fmaxf(q_raw[(ii >> 7) * N_DIM + n0 + (ii & 127)], 0.0f) + 1e-12f);
    }
    int l15 = lane & 15, l4 = lane >> 4;
    f32x4 acc[4][4] = {};
    #pragma unroll
    for (int kk = 0; kk < 2; ++kk) {
        bf16x8 bxh[4], bxl[4];
        #pragma unroll
        for (int ni = 0; ni < 4; ++ni) {
            int b = row0 + wc * 64 + ni * 16 + l15;
            size_t off = (size_t)b * 64 + kk * 32 + l4 * 8;
            bxh[ni] = *(const bf16x8*)(xh + off);
            bxl[ni] = *(const bf16x8*)(xl + off);
        }
        #pragma unroll
        for (int mi = 0; mi < 4; ++mi) {
            int n = n0 + wr * 64 + mi * 16 + l15;
            size_t off = (size_t)n * 64 + kk * 32 + l4 * 8;
            bf16x8 arh = *(const bf16x8*)(Rh + off);
            bf16x8 arl = *(const bf16x8*)(Rl + off);
            #pragma unroll
            for (int ni = 0; ni < 4; ++ni) {
                acc[mi][ni] = __builtin_amdgcn_mfma_f32_16x16x32_bf16(arh, bxh[ni], acc[mi][ni], 0, 0, 0);
                acc[mi][ni] = __builtin_amdgcn_mfma_f32_16x16x32_bf16(arh, bxl[ni], acc[mi][ni], 0, 0, 0);
                acc[mi][ni] = __builtin_amdgcn_mfma_f32_16x16x32_bf16(arl, bxh[ni], acc[mi][ni], 0, 0, 0);
            }
        }
    }
    #pragma unroll
    for (int mi = 0; mi < 4; ++mi) {
        int keyb = wr * 64 + mi * 16 + l4 * 4;          // 4 consecutive local keys
        f32x4 r2v = *(const f32x4*)(r2 + n0 + keyb);
        #pragma unroll
        for (int ni = 0; ni < 4; ++ni) {
            int bloc = wc * 64 + ni * 16 + l15;
            bf16x4 ev;
            #pragma unroll
            for (int j = 0; j < 4; ++j) {
                float s = acc[mi][ni][j] - r2v[j];
                ev[j] = (bf16)exp2f(s * LOG2E);
            }
            *(bf16x4*)(&eT[bloc][keyb]) = ev;
        }
    }
    __syncthreads();
    {
        int bloc = t >> 1, half = t & 1;
        int b = row0 + bloc;
        bf16x8 chunk[8];
        #pragma unroll
        for (int i = 0; i < 8; ++i)
            chunk[i] = *(const bf16x8*)(&eT[bloc][half * 64 + i * 8]);
        bf16x8* gp = (bf16x8*)(e + (size_t)b * N_DIM + n0 + half * 64);
        #pragma unroll
        for (int i = 0; i < 8; ++i) gp[i] = chunk[i];
        float s0 = 0, s1 = 0, s2 = 0, s3 = 0;
        #pragma unroll
        for (int i = 0; i < 8; ++i) {
            #pragma unroll
            for (int jj = 0; jj < 8; ++jj) {
                int nl = half * 64 + i * 8 + jj;
                float ef = (float)chunk[i][jj];
                s0 += ef * qp[0][nl]; s1 += ef * qp[1][nl];
                s2 += ef * qp[2][nl]; s3 += ef * qp[3][nl];
            }
        }
        s0 += __shfl_xor(s0, 1, 64);
        s1 += __shfl_xor(s1, 1, 64);
        s2 += __shfl_xor(s2, 1, 64);
        s3 += __shfl_xor(s3, 1, 64);
        if (half == 0) {
            f32x4 sv = {s0, s1, s2, s3};
            *(f32x4*)(Spart + ((size_t)blockIdx.x * B_DIM + b) * 4) = sv;
        }
    }
}

// K2b: Sinv[b][h] = 1 / (sum_kt Spart[kt][b][h] + eps)
__global__ void k_sreduce(const float* __restrict__ Spart, float* __restrict__ Sinv) {
    int i = blockIdx.x * 256 + threadIdx.x;     // 8192 = 2048*4
    float s = 0.f;
    #pragma unroll 8
    for (int kt = 0; kt < N_DIM / 128; ++kt) s += Spart[(size_t)kt * (B_DIM * 4) + i];
    Sinv[i] = 1.0f / (s + 1e-12f);
}

// K3: split-K GEMM  parts[z][2048][1024] = e @ Vt^T (K-slice z)
// ROUND 10 (round-9 post-mortem): 4-deep/128KB gave conflicts=0 and
// FETCH=98MB~ideal but only 104us -- 1 block/CU (1 wave/SIMD) exposed every
// ds_read->MFMA stall (1950cy/K-step vs ~300 floor; MfmaUtil flat 26.5%).
// Occupancy was the gate, not conflicts/fetch. This round:
//   - 2-deep buffers (64KB) -> 2 blocks/CU = 8 waves/CU (2/SIMD TLP)
//   - same counted vmcnt: steady vmcnt(8), tail 8/0; raw s_barrier; T2
//     swizzle (verified: conflicts 25.2M -> 0); T5 setprio; T1 XCD swizzle
//   - STAGE(t+2) AFTER trailing barrier (WAR-safe: compute(t)'s reads of
//     buf[t&1] retired before that barrier; ~1 iter lead covers L2 ~200cy)
//   - ksplit 8 -> 4: 512 blocks = exactly 2/CU, ONE batch (no serialized
//     prologues), parts traffic halved (WRITE 65->33MB, k_final reads half)
// vmcnt ledger: 8 loads/wave/STAGE; prologue 16 out; iter t: vmcnt(8) waits
// tile t (tile t+1's 8 remain), stage t+2 -> 16 out. Tail: vmcnt(8), then
// vmcnt(0). kiters=64 (>=3 for all fallbacks).
__launch_bounds__(256)
__global__ void k_gemm(const bf16* __restrict__ e, const bf16* __restrict__ Vt,
                       float* __restrict__ parts, int kiters) {
    __shared__ bf16 AB[2][2][8192];      // [buf][A/B][128 rows x 64 k] = 64 KB
    int t = threadIdx.x;
    int lane = t & 63, w = t >> 6;
    int wr = w >> 1, wc = w & 1;
    // --- XCD swizzle (T1; FETCH 279->70MB at round 5, ~ideal at round 9) ---
    int nwg = gridDim.x * gridDim.y * gridDim.z;
    int cpx = nwg >> 3;
    int flat = blockIdx.x + 8 * (blockIdx.y + 16 * blockIdx.z);
    int orig = (flat & 7) * cpx + (flat >> 3);
    int bx = orig & 7;
    int by = (orig >> 3) & 15;
    int bz = orig >> 7;
    int brow = by * 128;
    int bcol = bx * 128;
    int kbase = bz * kiters * 64;
    int l15 = lane & 15, l4 = lane >> 4;
    const char* eC  = (const char*)e;
    const char* VtC = (const char*)Vt;
    // pre-swizzled source column within the 128B row segment:
    // dest (linear) col = (lane&7)*16, row&7 = lane>>3  ->  src col = dest ^ ((row&7)<<4)
    int scolswz = (((lane & 7) ^ (lane >> 3)) << 4);
    int srow = lane >> 3;

#define STAGE(bi, tile) do {                                                              \
    size_t acol = (size_t)(kbase + (tile) * 64) * 2 + scolswz;                            \
    _Pragma("unroll")                                                                     \
    for (int j_ = 0; j_ < 4; ++j_) {                                                      \
        int chunk_ = j_ * 4 + w;                                                          \
        int row_ = chunk_ * 8 + srow;                                                     \
        __builtin_amdgcn_global_load_lds(                                                 \
            (const __attribute__((address_space(1))) void*)(eC + (size_t)(brow + row_) * (N_DIM*2) + acol), \
            (__attribute__((address_space(3))) void*)((char*)&AB[bi][0][0] + chunk_ * 1024), 16, 0, 0); \
        __builtin_amdgcn_global_load_lds(                                                 \
            (const __attribute__((address_space(1))) void*)(VtC + (size_t)(bcol + row_) * (N_DIM*2) + acol), \
            (__attribute__((address_space(3))) void*)((char*)&AB[bi][1][0] + chunk_ * 1024), 16, 0, 0); \
    }                                                                                     \
} while (0)

#define COMPUTE(bi) do {                                                                  \
    const bf16* As_ = &AB[bi][0][0];                                                      \
    const bf16* Bs_ = &AB[bi][1][0];                                                      \
    _Pragma("unroll")                                                                     \
    for (int kk = 0; kk < 2; ++kk) {                                                      \
        bf16x8 bfr[4], afr[4];                                                            \
        _Pragma("unroll")                                                                 \
        for (int ni = 0; ni < 4; ++ni) {                                                  \
            int row_ = wc * 64 + ni * 16 + l15;                                           \
            int col_ = (kk * 32 + l4 * 8) ^ ((row_ & 7) << 3);                            \
            bfr[ni] = *(const bf16x8*)(Bs_ + row_ * 64 + col_);                           \
        }                                                                                 \
        _Pragma("unroll")                                                                 \
        for (int mi = 0; mi < 4; ++mi) {                                                  \
            int row_ = wr * 64 + mi * 16 + l15;                                           \
            int col_ = (kk * 32 + l4 * 8) ^ ((row_ & 7) << 3);                            \
            afr[mi] = *(const bf16x8*)(As_ + row_ * 64 + col_);                           \
        }                                                                                 \
        _Pragma("unroll")                                                                 \
        for (int mi = 0; mi < 4; ++mi)                                                    \
            _Pragma("unroll")                                                             \
            for (int ni = 0; ni < 4; ++ni)                                                \
                acc[mi][ni] = __builtin_amdgcn_mfma_f32_16x16x32_bf16(afr[mi], bfr[ni], acc[mi][ni], 0, 0, 0); \
    }                                                                                     \
} while (0)

    f32x4 acc[4][4] = {};
    // prologue: prefetch tiles 0,1 into bufs 0,1 (16 loads in flight/wave)
    STAGE(0, 0);
    STAGE(1, 1);
    // main loop: wait tile t (8 newer stay in flight), compute t, stage t+2
    for (int kt = 0; kt <= kiters - 3; ++kt) {
        int bi = kt & 1;
        asm volatile("s_waitcnt vmcnt(8)" ::: "memory");
        __builtin_amdgcn_sched_barrier(0);
        asm volatile("s_barrier" ::: "memory");
        __builtin_amdgcn_s_setprio(1);
        COMPUTE(bi);
        __builtin_amdgcn_s_setprio(0);
        asm volatile("s_barrier" ::: "memory");
        STAGE(bi, kt + 2);               // buf (kt+2)&1 == kt&1
    }
    // 2-step tail: vmcnt 8 / 0
    {
        asm volatile("s_waitcnt vmcnt(8)" ::: "memory");
        __builtin_amdgcn_sched_barrier(0);
        asm volatile("s_barrier" ::: "memory");
        COMPUTE((kiters - 2) & 1);
        asm volatile("s_barrier" ::: "memory");
    }
    {
        asm volatile("s_waitcnt vmcnt(0)" ::: "memory");
        __builtin_amdgcn_sched_barrier(0);
        asm volatile("s_barrier" ::: "memory");
        COMPUTE((kiters - 1) & 1);
    }
#undef STAGE
#undef COMPUTE
    float* P = parts + (size_t)bz * ((size_t)B_DIM * NOUT);
    #pragma unroll
    for (int mi = 0; mi < 4; ++mi) {
        #pragma unroll
        for (int j = 0; j < 4; ++j) {
            int r = brow + wr * 64 + mi * 16 + l4 * 4 + j;
            #pragma unroll
            for (int ni = 0; ni < 4; ++ni) {
                int c = bcol + wc * 64 + ni * 16 + l15;
                P[(size_t)r * NOUT + c] = acc[mi][ni][j];
            }
        }
    }
}

// K4: out[b][c] = (sum_z parts[z][b][c]) * Sinv[b][c>>8]
__global__ void k_final(const float* __restrict__ parts, const float* __restrict__ Sinv,
                        float* __restrict__ out, int nks) {
    int i4 = blockIdx.x * 256 + threadIdx.x;    // 524288 quads
    size_t base = (size_t)i4 * 4;
    f32x4 s = {0.f, 0.f, 0.f, 0.f};
    for (int k = 0; k < nks; ++k)
        s += *(const f32x4*)(parts + (size_t)k * ((size_t)B_DIM * NOUT) + base);
    int b = i4 >> 8;
    int c = (i4 << 2) & 1023;
    float inv = Sinv[b * 4 + (c >> 8)];
    *(f32x4*)(out + base) = s * inv;
}

extern "C" void kernel_launch(void* const* d_in, const int* in_sizes, int n_in,
                              void* d_out, int out_size, void* d_ws, size_t ws_size,
                              hipStream_t stream) {
    const float* x     = (const float*)d_in[0];   // (2048, 64)
    const float* R     = (const float*)d_in[1];   // (16384, 64)
    const float* q_raw = (const float*)d_in[2];   // (4, 16384)
    const float* W     = (const float*)d_in[3];   // (4, 16384, 256)
    float* out = (float*)d_out;                    // (2048, 4, 256)

    char* ws = (char*)d_ws;
    size_t off = 0;
    auto alloc = [&](size_t bytes) {
        void* p = ws + off;
        off += (bytes + 255) & ~(size_t)255;
        return p;
    };
    bf16*  Vt    = (bf16*) alloc((size_t)NOUT * N_DIM * 2);          // 32 MB
    bf16*  eM    = (bf16*) alloc((size_t)B_DIM * N_DIM * 2);         // 64 MB
    bf16*  xh    = (bf16*) alloc((size_t)B_DIM * D_DIM * 2);
    bf16*  xl    = (bf16*) alloc((size_t)B_DIM * D_DIM * 2);
    bf16*  Rh    = (bf16*) alloc((size_t)N_DIM * D_DIM * 2);
    bf16*  Rl    = (bf16*) alloc((size_t)N_DIM * D_DIM * 2);
    float* r2    = (float*)alloc((size_t)N_DIM * 4);
    float* Spart = (float*)alloc((size_t)(N_DIM / 128) * B_DIM * 4 * 4);  // 4 MB
    float* Sinv  = (float*)alloc((size_t)B_DIM * H_DIM * 4);
    (void)n_in; (void)in_sizes;

    const size_t PART_BYTES = (size_t)B_DIM * NOUT * 4;              // 8 MB
    // ksplit=4: 512 blocks = exactly 2/CU with 64KB LDS, one batch.
    int ksplit = (ws_size >= off + 4 * PART_BYTES) ? 4 : 2;
    float* parts = (float*)alloc((size_t)ksplit * PART_BYTES);
    int kiters = N_DIM / (64 * ksplit);

    k_prep<<<dim3(PREP_RBLK + PREP_XBLK), 256, 0, stream>>>(x, R, xh, xl, Rh, Rl, r2);
    k_build_V<<<dim3(N_DIM / 64, DOUT_DIM / 32, H_DIM), 256, 0, stream>>>(W, q_raw, Vt);
    k_scores<<<dim3(N_DIM / 128, B_DIM / 128), 256, 0, stream>>>(xh, xl, Rh, Rl, r2, q_raw, eM, Spart);
    k_sreduce<<<dim3(B_DIM * H_DIM / 256), 256, 0, stream>>>(Spart, Sinv);
    k_gemm<<<dim3(NOUT / 128, B_DIM / 128, ksplit), 256, 0, stream>>>(eM, Vt, parts, kiters);
    k_final<<<dim3(B_DIM * NOUT / 4 / 256), 256, 0, stream>>>(parts, Sinv, out, ksplit);
}